// Round 1
// baseline (593.956 us; speedup 1.0000x reference)
//
#include <hip/hip_runtime.h>
#include <cstdint>

// Problem dims (compile-time)
#define B_DIM 8192
#define IN_DIM 1024
#define H_DIM 2048
#define KCAT 3072  // IN + H

typedef __attribute__((ext_vector_type(8))) __bf16 bf16x8;
typedef __attribute__((ext_vector_type(4))) float f32x4;

// ---------- helpers ----------
__device__ __forceinline__ unsigned short f2bf(float f) {
  unsigned int u = __float_as_uint(f);
  unsigned int r = (u + 0x7fffu + ((u >> 16) & 1u)) >> 16;
  return (unsigned short)r;
}
__device__ __forceinline__ float bf2f(unsigned short s) {
  return __uint_as_float(((unsigned int)s) << 16);
}
__device__ __forceinline__ float sigmoidf_(float x) {
  return 1.0f / (1.0f + __expf(-x));
}
__device__ __forceinline__ float tanhf_(float x) {
  float xc = fminf(fmaxf(x, -15.f), 15.f);
  float t = __expf(2.f * xc);
  return (t - 1.f) / (t + 1.f);
}
__device__ __forceinline__ void gload16(const unsigned short* g, unsigned short* l) {
  __builtin_amdgcn_global_load_lds(
      (const __attribute__((address_space(1))) unsigned int*)(g),
      (__attribute__((address_space(3))) unsigned int*)(l),
      16, 0, 0);
}

// ---------- fp32 -> bf16 strided convert (pack) ----------
__global__ void cvt_kernel(const float* __restrict__ src, unsigned short* __restrict__ dst,
                           int rows, int cols, int src_ld, int dst_ld) {
  long long idx = ((long long)blockIdx.x * blockDim.x + threadIdx.x) * 4;
  long long total = (long long)rows * cols;
  if (idx >= total) return;
  int r = (int)(idx / cols);
  int c = (int)(idx - (long long)r * cols);
  const float4 v = *(const float4*)(src + (long long)r * src_ld + c);
  ushort4 o;
  o.x = f2bf(v.x); o.y = f2bf(v.y); o.z = f2bf(v.z); o.w = f2bf(v.w);
  *(ushort4*)(dst + (long long)r * dst_ld + c) = o;
}

// ---------- fused bf16 GEMM (C = A * W^T), m97-style 128x128 tile ----------
// MODE 0: N=4096.  n<H: r-gate -> a = sigmoid(v+b_r)*h_prev  -> xa[m*KCAT+IN+n] (bf16)
//                  n>=H: z-gate -> zout[m*H + (n-H)] = sigmoid(v+b_z) (fp32, stashed in d_out)
// MODE 1: N=2048.  h_tilde = tanh(v+b_h); out = (1-z)*h + z*h_tilde (fp32)
template <int MODE>
__global__ __launch_bounds__(256) void gemm_fused(
    const unsigned short* __restrict__ A,  // M x K bf16, ld=K
    const unsigned short* __restrict__ W,  // N x K bf16, ld=K
    int M, int N, int K,
    const float* __restrict__ bias0,       // b_r (MODE0) / b_h (MODE1)
    const float* __restrict__ bias1,       // b_z (MODE0)
    const float* __restrict__ h_prev,
    unsigned short* __restrict__ xa,       // MODE0 write target
    float* __restrict__ zbuf,              // MODE0: write z ; MODE1: read z
    float* __restrict__ out) {             // MODE1 write target
  __shared__ unsigned short lA[128 * 32];
  __shared__ unsigned short lB[128 * 32];

  const int tid = threadIdx.x;
  const int lane = tid & 63;
  const int wave = tid >> 6;
  const int wm = wave >> 1;  // 0..1
  const int wn = wave & 1;   // 0..1
  const int bm = blockIdx.y * 128;
  const int bn = blockIdx.x * 128;

  f32x4 acc[4][4] = {};

  const int arow = tid >> 2;         // 0..63
  const int acol = (tid & 3) << 3;   // 0,8,16,24
  const unsigned short* gA = A + (long long)(bm + arow) * K + acol;
  const unsigned short* gB = W + (long long)(bn + arow) * K + acol;
  unsigned short* lAp0 = &lA[tid * 8];
  unsigned short* lAp1 = &lA[2048 + tid * 8];
  unsigned short* lBp0 = &lB[tid * 8];
  unsigned short* lBp1 = &lB[2048 + tid * 8];
  const long long rowskip = 64LL * K;

  const int kq = (lane >> 4) << 3;  // 0,8,16,24
  const int fr = lane & 15;

  for (int k0 = 0; k0 < K; k0 += 32) {
    gload16(gA + k0, lAp0);
    gload16(gA + rowskip + k0, lAp1);
    gload16(gB + k0, lBp0);
    gload16(gB + rowskip + k0, lBp1);
    __syncthreads();

    bf16x8 af[4], bfv[4];
#pragma unroll
    for (int i = 0; i < 4; i++)
      af[i] = *(const bf16x8*)&lA[(wm * 64 + i * 16 + fr) * 32 + kq];
#pragma unroll
    for (int j = 0; j < 4; j++)
      bfv[j] = *(const bf16x8*)&lB[(wn * 64 + j * 16 + fr) * 32 + kq];
#pragma unroll
    for (int i = 0; i < 4; i++)
#pragma unroll
      for (int j = 0; j < 4; j++)
        acc[i][j] = __builtin_amdgcn_mfma_f32_16x16x32_bf16(af[i], bfv[j], acc[i][j], 0, 0, 0);
    __syncthreads();
  }

  // Epilogue. C/D layout: col = lane&15, row = (lane>>4)*4 + reg  [m89/m91]
  const int cr = (lane >> 4) << 2;
  const int cc = lane & 15;
#pragma unroll
  for (int i = 0; i < 4; i++) {
#pragma unroll
    for (int j = 0; j < 4; j++) {
#pragma unroll
      for (int e = 0; e < 4; e++) {
        const int m = bm + wm * 64 + i * 16 + cr + e;
        const int n = bn + wn * 64 + j * 16 + cc;
        const float v = acc[i][j][e];
        if (MODE == 0) {
          if (n < H_DIM) {
            const float g = sigmoidf_(v + bias0[n]);
            const float a = g * h_prev[(long long)m * H_DIM + n];
            xa[(long long)m * KCAT + IN_DIM + n] = f2bf(a);
          } else {
            const int nz = n - H_DIM;
            const float g = sigmoidf_(v + bias1[nz]);
            zbuf[(long long)m * H_DIM + nz] = g;
          }
        } else {
          const float ht = tanhf_(v + bias0[n]);
          const long long off = (long long)m * H_DIM + n;
          const float z = zbuf[off];
          const float h = h_prev[off];
          out[off] = (1.f - z) * h + z * ht;
        }
      }
    }
  }
}

// ---------- launch ----------
static inline void launch_cvt(const float* src, unsigned short* dst, int rows, int cols,
                              int src_ld, int dst_ld, hipStream_t stream) {
  long long total = (long long)rows * cols;
  int threads = 256;
  int blocks = (int)((total / 4 + threads - 1) / threads);
  cvt_kernel<<<blocks, threads, 0, stream>>>(src, dst, rows, cols, src_ld, dst_ld);
}

extern "C" void kernel_launch(void* const* d_in, const int* in_sizes, int n_in,
                              void* d_out, int out_size, void* d_ws, size_t ws_size,
                              hipStream_t stream) {
  const float* x    = (const float*)d_in[0];   // (B, IN)
  const float* h    = (const float*)d_in[1];   // (B, H)
  const float* W_ir = (const float*)d_in[2];   // (H, IN)
  const float* W_iz = (const float*)d_in[3];
  const float* W_ih = (const float*)d_in[4];
  const float* W_hr = (const float*)d_in[5];   // (H, H)
  const float* W_hz = (const float*)d_in[6];
  const float* W_hh = (const float*)d_in[7];
  const float* b_r  = (const float*)d_in[8];
  const float* b_z  = (const float*)d_in[9];
  const float* b_h  = (const float*)d_in[10];
  float* out = (float*)d_out;

  // workspace layout (bytes)
  char* ws = (char*)d_ws;
  unsigned short* xh  = (unsigned short*)(ws);                      // B x KCAT bf16  (50,331,648 B)
  unsigned short* xa  = (unsigned short*)(ws + 50331648LL);         // B x KCAT bf16
  unsigned short* Wrz = (unsigned short*)(ws + 100663296LL);        // 2H x KCAT bf16 (25,165,824 B)
  unsigned short* Wh  = (unsigned short*)(ws + 125829120LL);        // H x KCAT bf16  (12,582,912 B)
  // z is stashed fp32 in d_out between GEMM_A and GEMM_B.

  // ---- pack inputs & weights to bf16 ----
  launch_cvt(x, xh, B_DIM, IN_DIM, IN_DIM, KCAT, stream);
  launch_cvt(h, xh + IN_DIM, B_DIM, H_DIM, H_DIM, KCAT, stream);
  launch_cvt(x, xa, B_DIM, IN_DIM, IN_DIM, KCAT, stream);
  launch_cvt(W_ir, Wrz, H_DIM, IN_DIM, IN_DIM, KCAT, stream);
  launch_cvt(W_hr, Wrz + IN_DIM, H_DIM, H_DIM, H_DIM, KCAT, stream);
  launch_cvt(W_iz, Wrz + (long long)H_DIM * KCAT, H_DIM, IN_DIM, IN_DIM, KCAT, stream);
  launch_cvt(W_hz, Wrz + (long long)H_DIM * KCAT + IN_DIM, H_DIM, H_DIM, H_DIM, KCAT, stream);
  launch_cvt(W_ih, Wh, H_DIM, IN_DIM, IN_DIM, KCAT, stream);
  launch_cvt(W_hh, Wh + IN_DIM, H_DIM, H_DIM, H_DIM, KCAT, stream);

  // ---- GEMM_A: [x|h] @ Wrz^T -> r,z gates; writes a into xa, z into d_out ----
  {
    dim3 grid(4096 / 128, B_DIM / 128);
    gemm_fused<0><<<grid, 256, 0, stream>>>(xh, Wrz, B_DIM, 2 * H_DIM, KCAT,
                                            b_r, b_z, h, xa, out, nullptr);
  }
  // ---- GEMM_B: [x|a] @ Wh^T -> h_tilde; final h_t into d_out ----
  {
    dim3 grid(2048 / 128, B_DIM / 128);
    gemm_fused<1><<<grid, 256, 0, stream>>>(xa, Wh, B_DIM, H_DIM, KCAT,
                                            b_h, nullptr, h, nullptr, out, out);
  }
}

// Round 2
// 492.738 us; speedup vs baseline: 1.2054x; 1.2054x over previous
//
#include <hip/hip_runtime.h>
#include <cstdint>

// Problem dims (compile-time)
#define B_DIM 8192
#define IN_DIM 1024
#define H_DIM 2048
#define KCAT 3072  // IN + H

typedef __attribute__((ext_vector_type(8))) __bf16 bf16x8;
typedef __attribute__((ext_vector_type(4))) float f32x4;

// ---------- helpers ----------
__device__ __forceinline__ unsigned short f2bf(float f) {
  unsigned int u = __float_as_uint(f);
  unsigned int r = (u + 0x7fffu + ((u >> 16) & 1u)) >> 16;
  return (unsigned short)r;
}
__device__ __forceinline__ float sigmoidf_(float x) {
  return 1.0f / (1.0f + __expf(-x));
}
__device__ __forceinline__ float tanhf_(float x) {
  float xc = fminf(fmaxf(x, -15.f), 15.f);
  float t = __expf(2.f * xc);
  return (t - 1.f) / (t + 1.f);
}
__device__ __forceinline__ void gload16(const unsigned short* g, unsigned short* l) {
  __builtin_amdgcn_global_load_lds(
      (const __attribute__((address_space(1))) unsigned int*)(g),
      (__attribute__((address_space(3))) unsigned int*)(l),
      16, 0, 0);
}

// ---------- fp32 -> bf16 strided convert (pack) ----------
__global__ void cvt_kernel(const float* __restrict__ src, unsigned short* __restrict__ dst,
                           int rows, int cols, int src_ld, int dst_ld) {
  long long idx = ((long long)blockIdx.x * blockDim.x + threadIdx.x) * 4;
  long long total = (long long)rows * cols;
  if (idx >= total) return;
  int r = (int)(idx / cols);
  int c = (int)(idx - (long long)r * cols);
  const float4 v = *(const float4*)(src + (long long)r * src_ld + c);
  ushort4 o;
  o.x = f2bf(v.x); o.y = f2bf(v.y); o.z = f2bf(v.z); o.w = f2bf(v.w);
  *(ushort4*)(dst + (long long)r * dst_ld + c) = o;
}

// ---------- 256x256 bf16 GEMM (C = A * W^T), BK=64, 8 waves, dbuf LDS,
// T2 XOR-swizzle (inverse-swz source + swz read), counted vmcnt(8), raw barriers.
// MODE 0: n<H: a = sigmoid(v+b_r)*h_prev -> xa ; n>=H: z = sigmoid(v+b_z) -> zbuf
// MODE 1: h_tilde = tanh(v+b_h); out = (1-z)*h + z*h_tilde
template <int MODE>
__global__ __launch_bounds__(512) void gemm256(
    const unsigned short* __restrict__ A,  // M x K bf16, ld=K
    const unsigned short* __restrict__ W,  // N x K bf16, ld=K
    int K, int NTILN,
    const float* __restrict__ bias0,
    const float* __restrict__ bias1,
    const float* __restrict__ h_prev,
    unsigned short* __restrict__ xa,
    float* __restrict__ zbuf,
    float* __restrict__ out) {
  __shared__ unsigned short lA[2][256 * 64];  // 32 KiB each
  __shared__ unsigned short lB[2][256 * 64];

  const int tid = threadIdx.x;
  const int lane = tid & 63;
  const int wave = tid >> 6;  // 0..7
  const int wm = wave >> 2;   // 0..1  (M half)
  const int wn = wave & 3;    // 0..3  (N quarter)

  // T1: XCD-aware block swizzle (nwg % 8 == 0 for both GEMMs)
  const int nwg = gridDim.x;
  const int cpx = nwg >> 3;
  const int bid = blockIdx.x;
  const int swz = (bid & 7) * cpx + (bid >> 3);
  const int bn = (swz % NTILN) * 256;
  const int bm = (swz / NTILN) * 256;

  const int NT = K >> 6;  // K-tiles of 64

  // ---- staging addresses (inverse-swizzled global source, linear LDS dest) ----
  // dest linear byte (per round r): r*8192 + tid*16  -> row = r*64 + (tid>>3), slot = tid&7
  // physical layout holds logical col-byte  (slot^(row&7))*16  at that slot.
  const int srow = tid >> 3;  // 0..63
  const int slot = tid & 7;
  const int scol = ((slot ^ (srow & 7)) << 3);  // element offset within 64-elem k-chunk
  const unsigned short* gAs = A + (long long)(bm + srow) * K + scol;
  const unsigned short* gBs = W + (long long)(bn + srow) * K + scol;
  const long long rstep = 64LL * K;

  // ---- ds_read addressing (swizzled) ----
  const int fr = lane & 15;
  const int kq2 = ((lane >> 4) << 4);  // byte offset of k-quad (0,16,32,48)
  const int xs = (fr & 7) << 4;
  const int c0 = (0 + kq2) ^ xs;   // k-slice 0 byte-in-row
  const int c1 = (64 + kq2) ^ xs;  // k-slice 1 byte-in-row

  f32x4 acc[8][4] = {};

  // ---- prologue: stage tiles 0 and 1 ----
  {
    unsigned short* da = &lA[0][tid * 8];
    unsigned short* db = &lB[0][tid * 8];
#pragma unroll
    for (int r = 0; r < 4; r++) {
      gload16(gAs + r * rstep, da + r * 4096);
      gload16(gBs + r * rstep, db + r * 4096);
    }
    da = &lA[1][tid * 8];
    db = &lB[1][tid * 8];
#pragma unroll
    for (int r = 0; r < 4; r++) {
      gload16(gAs + 64 + r * rstep, da + r * 4096);
      gload16(gBs + 64 + r * rstep, db + r * 4096);
    }
  }
  asm volatile("s_waitcnt vmcnt(8)" ::: "memory");
  __builtin_amdgcn_s_barrier();

  for (int t = 0; t < NT; ++t) {
    const int p = t & 1;
    const char* Ab = (const char*)&lA[p][0];
    const char* Bb = (const char*)&lB[p][0];

    // B fragments (all 4 N-frags, both k-slices)
    bf16x8 Br[4][2];
#pragma unroll
    for (int j = 0; j < 4; j++) {
      const int row = wn * 64 + j * 16 + fr;
      Br[j][0] = *(const bf16x8*)(Bb + row * 128 + c0);
      Br[j][1] = *(const bf16x8*)(Bb + row * 128 + c1);
    }
    // A low half (M-frags 0..3)
    bf16x8 Alo[4][2];
#pragma unroll
    for (int i = 0; i < 4; i++) {
      const int row = wm * 128 + i * 16 + fr;
      Alo[i][0] = *(const bf16x8*)(Ab + row * 128 + c0);
      Alo[i][1] = *(const bf16x8*)(Ab + row * 128 + c1);
    }
    __builtin_amdgcn_s_setprio(1);
#pragma unroll
    for (int i = 0; i < 4; i++)
#pragma unroll
      for (int j = 0; j < 4; j++) {
        acc[i][j] = __builtin_amdgcn_mfma_f32_16x16x32_bf16(Alo[i][0], Br[j][0], acc[i][j], 0, 0, 0);
        acc[i][j] = __builtin_amdgcn_mfma_f32_16x16x32_bf16(Alo[i][1], Br[j][1], acc[i][j], 0, 0, 0);
      }
    __builtin_amdgcn_s_setprio(0);

    // A high half (M-frags 4..7)
    bf16x8 Ahi[4][2];
#pragma unroll
    for (int i = 0; i < 4; i++) {
      const int row = wm * 128 + 64 + i * 16 + fr;
      Ahi[i][0] = *(const bf16x8*)(Ab + row * 128 + c0);
      Ahi[i][1] = *(const bf16x8*)(Ab + row * 128 + c1);
    }
    // all LDS reads of buf[p] retired in every wave -> buf[p] dead
    asm volatile("s_waitcnt lgkmcnt(0)" ::: "memory");
    __builtin_amdgcn_sched_barrier(0);
    __builtin_amdgcn_s_barrier();

    // stage tile t+2 into the now-dead buffer (stays in flight across barriers)
    {
      const int t2 = (t + 2 < NT) ? t + 2 : NT - 1;
      const unsigned short* ga = gAs + (long long)t2 * 64;
      const unsigned short* gb = gBs + (long long)t2 * 64;
      unsigned short* da = &lA[p][tid * 8];
      unsigned short* db = &lB[p][tid * 8];
#pragma unroll
      for (int r = 0; r < 4; r++) {
        gload16(ga + r * rstep, da + r * 4096);
        gload16(gb + r * rstep, db + r * 4096);
      }
    }

    __builtin_amdgcn_s_setprio(1);
#pragma unroll
    for (int i = 0; i < 4; i++)
#pragma unroll
      for (int j = 0; j < 4; j++) {
        acc[i + 4][j] = __builtin_amdgcn_mfma_f32_16x16x32_bf16(Ahi[i][0], Br[j][0], acc[i + 4][j], 0, 0, 0);
        acc[i + 4][j] = __builtin_amdgcn_mfma_f32_16x16x32_bf16(Ahi[i][1], Br[j][1], acc[i + 4][j], 0, 0, 0);
      }
    __builtin_amdgcn_s_setprio(0);

    // t+1's 8 loads complete; only t+2's 8 remain outstanding (never drain to 0)
    asm volatile("s_waitcnt vmcnt(8)" ::: "memory");
    __builtin_amdgcn_sched_barrier(0);
    __builtin_amdgcn_s_barrier();
  }

  // ---- fused epilogue. C/D layout: col = lane&15, row = (lane>>4)*4 + reg ----
  const int cr = (lane >> 4) << 2;
  const int cc = lane & 15;
#pragma unroll
  for (int i = 0; i < 8; i++) {
#pragma unroll
    for (int j = 0; j < 4; j++) {
#pragma unroll
      for (int e = 0; e < 4; e++) {
        const int m = bm + wm * 128 + i * 16 + cr + e;
        const int n = bn + wn * 64 + j * 16 + cc;
        const float v = acc[i][j][e];
        if (MODE == 0) {
          if (n < H_DIM) {
            const float g = sigmoidf_(v + bias0[n]);
            const float a = g * h_prev[(long long)m * H_DIM + n];
            xa[(long long)m * KCAT + IN_DIM + n] = f2bf(a);
          } else {
            const int nz = n - H_DIM;
            const float g = sigmoidf_(v + bias1[nz]);
            zbuf[(long long)m * H_DIM + nz] = g;
          }
        } else {
          const float ht = tanhf_(v + bias0[n]);
          const long long off = (long long)m * H_DIM + n;
          const float z = zbuf[off];
          const float h = h_prev[off];
          out[off] = (1.f - z) * h + z * ht;
        }
      }
    }
  }
}

// ---------- launch ----------
static inline void launch_cvt(const float* src, unsigned short* dst, int rows, int cols,
                              int src_ld, int dst_ld, hipStream_t stream) {
  long long total = (long long)rows * cols;
  int threads = 256;
  int blocks = (int)((total / 4 + threads - 1) / threads);
  cvt_kernel<<<blocks, threads, 0, stream>>>(src, dst, rows, cols, src_ld, dst_ld);
}

extern "C" void kernel_launch(void* const* d_in, const int* in_sizes, int n_in,
                              void* d_out, int out_size, void* d_ws, size_t ws_size,
                              hipStream_t stream) {
  const float* x    = (const float*)d_in[0];   // (B, IN)
  const float* h    = (const float*)d_in[1];   // (B, H)
  const float* W_ir = (const float*)d_in[2];   // (H, IN)
  const float* W_iz = (const float*)d_in[3];
  const float* W_ih = (const float*)d_in[4];
  const float* W_hr = (const float*)d_in[5];   // (H, H)
  const float* W_hz = (const float*)d_in[6];
  const float* W_hh = (const float*)d_in[7];
  const float* b_r  = (const float*)d_in[8];
  const float* b_z  = (const float*)d_in[9];
  const float* b_h  = (const float*)d_in[10];
  float* out = (float*)d_out;

  // workspace layout (bytes)
  char* ws = (char*)d_ws;
  unsigned short* xh  = (unsigned short*)(ws);                      // B x KCAT bf16
  unsigned short* xa  = (unsigned short*)(ws + 50331648LL);         // B x KCAT bf16
  unsigned short* Wrz = (unsigned short*)(ws + 100663296LL);        // 2H x KCAT bf16
  unsigned short* Wh  = (unsigned short*)(ws + 125829120LL);        // H x KCAT bf16
  // z is stashed fp32 in d_out between GEMM_A and GEMM_B.

  // ---- pack inputs & weights to bf16 ----
  launch_cvt(x, xh, B_DIM, IN_DIM, IN_DIM, KCAT, stream);
  launch_cvt(h, xh + IN_DIM, B_DIM, H_DIM, H_DIM, KCAT, stream);
  launch_cvt(x, xa, B_DIM, IN_DIM, IN_DIM, KCAT, stream);
  launch_cvt(W_ir, Wrz, H_DIM, IN_DIM, IN_DIM, KCAT, stream);
  launch_cvt(W_hr, Wrz + IN_DIM, H_DIM, H_DIM, H_DIM, KCAT, stream);
  launch_cvt(W_iz, Wrz + (long long)H_DIM * KCAT, H_DIM, IN_DIM, IN_DIM, KCAT, stream);
  launch_cvt(W_hz, Wrz + (long long)H_DIM * KCAT + IN_DIM, H_DIM, H_DIM, H_DIM, KCAT, stream);
  launch_cvt(W_ih, Wh, H_DIM, IN_DIM, IN_DIM, KCAT, stream);
  launch_cvt(W_hh, Wh + IN_DIM, H_DIM, H_DIM, H_DIM, KCAT, stream);

  // ---- GEMM_A: [x|h] @ Wrz^T -> r,z gates; writes a into xa, z into d_out ----
  {
    const int ntiln = 4096 / 256;                 // 16
    dim3 grid((B_DIM / 256) * ntiln);             // 512 blocks (%8==0)
    gemm256<0><<<grid, 512, 0, stream>>>(xh, Wrz, KCAT, ntiln,
                                         b_r, b_z, h, xa, out, nullptr);
  }
  // ---- GEMM_B: [x|a] @ Wh^T -> h_tilde; final h_t into d_out ----
  {
    const int ntiln = 2048 / 256;                 // 8
    dim3 grid((B_DIM / 256) * ntiln);             // 256 blocks (%8==0)
    gemm256<1><<<grid, 512, 0, stream>>>(xa, Wh, KCAT, ntiln,
                                         b_h, nullptr, h, nullptr, out, out);
  }
}

// Round 3
// 446.058 us; speedup vs baseline: 1.3316x; 1.1046x over previous
//
#include <hip/hip_runtime.h>
#include <cstdint>

// Problem dims (compile-time)
#define B_DIM 8192
#define IN_DIM 1024
#define H_DIM 2048
#define KC 3072     // IN + H (both GEMMs have K = 3072)
#define NTILES 96   // KC / 32

typedef __attribute__((ext_vector_type(8))) __bf16 bf16x8;
typedef __attribute__((ext_vector_type(4))) float f32x4;

// ---------- helpers ----------
__device__ __forceinline__ unsigned short f2bf(float f) {
  unsigned int u = __float_as_uint(f);
  unsigned int r = (u + 0x7fffu + ((u >> 16) & 1u)) >> 16;
  return (unsigned short)r;
}
__device__ __forceinline__ float sigmoidf_(float x) {
  return 1.0f / (1.0f + __expf(-x));
}
__device__ __forceinline__ float tanhf_(float x) {
  float xc = fminf(fmaxf(x, -15.f), 15.f);
  float t = __expf(2.f * xc);
  return (t - 1.f) / (t + 1.f);
}
__device__ __forceinline__ void gload16(const unsigned short* g, unsigned short* l) {
  __builtin_amdgcn_global_load_lds(
      (const __attribute__((address_space(1))) unsigned int*)(g),
      (__attribute__((address_space(3))) unsigned int*)(l),
      16, 0, 0);
}

// ---------- fp32 -> bf16 strided convert (pack) ----------
__global__ void cvt_kernel(const float* __restrict__ src, unsigned short* __restrict__ dst,
                           int rows, int cols, int src_ld, int dst_ld) {
  long long idx = ((long long)blockIdx.x * blockDim.x + threadIdx.x) * 4;
  long long total = (long long)rows * cols;
  if (idx >= total) return;
  int r = (int)(idx / cols);
  int c = (int)(idx - (long long)r * cols);
  const float4 v = *(const float4*)(src + (long long)r * src_ld + c);
  ushort4 o;
  o.x = f2bf(v.x); o.y = f2bf(v.y); o.z = f2bf(v.z); o.w = f2bf(v.w);
  *(ushort4*)(dst + (long long)r * dst_ld + c) = o;
}

// ---------- 256x256 bf16 GEMM (C = A * W^T), BK=32, 4 LDS slots, 8-phase ----------
// Per iteration: 2 K-tiles, 8 phases of 8 MFMA. Counted vmcnt (4/3/3), never 0.
// LDS pair-row swizzle: logical (row r, 16B-chunk c) -> slot (r>>1)*8 + (((r&1)<<2|c) ^ ((r>>1)&7)).
// MODE 0: n<H: a = sigmoid(v+b_r)*h_prev -> xa ; n>=H: z = sigmoid(v+b_z) -> zbuf
// MODE 1: h_tilde = tanh(v+b_h); out = (1-z)*h + z*h_tilde
#define SB0 __builtin_amdgcn_sched_barrier(0)
#define BAR __builtin_amdgcn_s_barrier()
#define VMC(n) asm volatile("s_waitcnt vmcnt(" #n ")" ::: "memory")
#define PRIO1 __builtin_amdgcn_s_setprio(1)
#define PRIO0 __builtin_amdgcn_s_setprio(0)

#define SLOTA(t) (&lds[(t) & 3][0][0])
#define SLOTB(t) (&lds[(t) & 3][1][0])
#define STAGE_(src, dstregion) gload16((src), (unsigned short*)(dstregion) + tid * 8)

#define RDA(dst, slotp, qmv)                                                        \
  _Pragma("unroll") for (int i_ = 0; i_ < 4; i_++)                                  \
      dst[i_] = *(const bf16x8*)((slotp) + ((wm * 128 + (qmv) * 64 + i_ * 16) << 6) + TC);
#define RDB1(dst, slotp, nf)                                                        \
  dst = *(const bf16x8*)((slotp) + ((wn * 64 + (nf) * 16) << 6) + TC);

#define MFMA8(Aset, Bset, qm, qn)                                                   \
  _Pragma("unroll") for (int i_ = 0; i_ < 4; i_++)                                  \
      _Pragma("unroll") for (int j_ = 0; j_ < 2; j_++)                              \
          acc[(qm) * 4 + i_][(qn) * 2 + j_] = __builtin_amdgcn_mfma_f32_16x16x32_bf16( \
              Aset[i_], Bset[(qn) * 2 + j_], acc[(qm) * 4 + i_][(qn) * 2 + j_], 0, 0, 0);

template <int MODE>
__global__ __launch_bounds__(512) void gemm256(
    const unsigned short* __restrict__ Alo_,  // A source for k-tiles < splitT
    const unsigned short* __restrict__ Ahi_,  // A source for k-tiles >= splitT
    int splitT,
    const unsigned short* __restrict__ Wm,    // N x K bf16
    int NTILN,
    const float* __restrict__ bias0,
    const float* __restrict__ bias1,
    const float* __restrict__ h_prev,
    unsigned short* __restrict__ xa,
    float* __restrict__ zbuf,
    float* __restrict__ out) {
  __shared__ char lds[4][2][16384];  // [slot][A/B][bytes] = 128 KiB

  const int tid = threadIdx.x;
  const int lane = tid & 63;
  const int wave = tid >> 6;
  const int wm = wave >> 2;  // 0..1
  const int wn = wave & 3;   // 0..3

  // T1: XCD-aware block swizzle (grid %8 == 0)
  const int nwg = gridDim.x;
  const int cpx = nwg >> 3;
  const int bid = blockIdx.x;
  const int swz = (bid & 7) * cpx + (bid >> 3);
  const int bn = (swz % NTILN) * 256;
  const int bm = (swz / NTILN) * 256;

  // ---- read-side thread constants ----
  const int fr = lane & 15;
  const int cq = lane >> 4;  // 16B chunk 0..3
  const int TC = ((fr & ~1) << 6) + (((((fr & 1) << 2) | cq) ^ ((fr >> 1) & 7)) << 4);

  // ---- stage-side constants (inverse of the pair-row swizzle) ----
  const int gs0 = tid;
  const int pp0 = (gs0 & 7) ^ ((gs0 >> 3) & 7);
  const int sr0 = ((gs0 >> 3) << 1) + (pp0 >> 2);
  const int sc0 = pp0 & 3;
  const int gs1 = 512 + tid;
  const int pp1 = (gs1 & 7) ^ ((gs1 >> 3) & 7);
  const int sr1 = ((gs1 >> 3) << 1) + (pp1 >> 2);
  const int sc1 = pp1 & 3;

  const long long offA0 = (long long)(bm + sr0) * KC + sc0 * 8;
  const long long offA1 = (long long)(bm + sr1) * KC + sc1 * 8;
  const long long offB0 = (long long)(bn + sr0) * KC + sc0 * 8;
  const long long offB1 = (long long)(bn + sr1) * KC + sc1 * 8;
  const unsigned short* gAlo0 = Alo_ + offA0;
  const unsigned short* gAhi0 = Ahi_ + offA0;
  const unsigned short* gAlo1 = Alo_ + offA1;
  const unsigned short* gAhi1 = Ahi_ + offA1;
  const unsigned short* gB0 = Wm + offB0;
  const unsigned short* gB1 = Wm + offB1;

  f32x4 acc[8][4] = {};

  // ---- prologue: stage tiles 0 and 1 fully (8 loads/thread) ----
  STAGE_(((0 < splitT) ? gAlo0 : gAhi0), SLOTA(0));
  STAGE_(((0 < splitT) ? gAlo1 : gAhi1), SLOTA(0) + 8192);
  STAGE_(gB0, SLOTB(0));
  STAGE_(gB1, SLOTB(0) + 8192);
  STAGE_(((1 < splitT) ? gAlo0 : gAhi0) + 32, SLOTA(1));
  STAGE_(((1 < splitT) ? gAlo1 : gAhi1) + 32, SLOTA(1) + 8192);
  STAGE_(gB0 + 32, SLOTB(1));
  STAGE_(gB1 + 32, SLOTB(1) + 8192);
  VMC(4);  // tile 0 landed; tile 1's 4 loads stay in flight
  BAR;

  bf16x8 ALo0[4], AHi0[4], ALo1[4], AHi1[4], Bf0[4], Bf1[4];
  RDA(ALo0, SLOTA(0), 0);
  RDB1(Bf0[0], SLOTB(0), 0);
  RDB1(Bf0[1], SLOTB(0), 1);

  for (int it = 0; it < NTILES / 2; ++it) {
    const int t0 = it * 2;
    const int t1 = t0 + 1;
    int s0 = t0 + 2; if (s0 > NTILES - 1) s0 = NTILES - 1;
    int s1 = t0 + 3; if (s1 > NTILES - 1) s1 = NTILES - 1;
    char* rA0 = SLOTA(t0); char* rB0 = SLOTB(t0);
    char* rA1 = SLOTA(t1); char* rB1 = SLOTB(t1);
    char* wA2 = SLOTA(t0 + 2); char* wB2 = SLOTB(t0 + 2);
    char* wA3 = SLOTA(t0 + 3); char* wB3 = SLOTB(t0 + 3);
    const unsigned short* sA0_0 = ((s0 < splitT) ? gAlo0 : gAhi0) + s0 * 32;
    const unsigned short* sA0_1 = ((s0 < splitT) ? gAlo1 : gAhi1) + s0 * 32;
    const unsigned short* sA1_0 = ((s1 < splitT) ? gAlo0 : gAhi0) + s1 * 32;
    const unsigned short* sA1_1 = ((s1 < splitT) ? gAlo1 : gAhi1) + s1 * 32;

    // ---- p1: MFMA (0,0) t0 ----
    SB0;
    RDB1(Bf0[2], rB0, 2); RDB1(Bf0[3], rB0, 3);
    STAGE_(sA0_0, wA2);
    SB0; BAR; SB0;
    PRIO1; MFMA8(ALo0, Bf0, 0, 0); PRIO0;
    // ---- p2: MFMA (0,1) t0 ----
    SB0;
    RDA(AHi0, rA0, 1);
    STAGE_(sA0_1, wA2 + 8192);
    SB0; VMC(4); BAR; SB0;
    PRIO1; MFMA8(ALo0, Bf0, 0, 1); PRIO0;
    // ---- p3: MFMA (1,0) t0 ----
    SB0;
    RDA(ALo1, rA1, 0);
    STAGE_(gB0 + s0 * 32, wB2);
    SB0; VMC(3); BAR; SB0;
    PRIO1; MFMA8(AHi0, Bf0, 1, 0); PRIO0;
    // ---- p4: MFMA (1,1) t0 ----
    SB0;
    RDB1(Bf1[0], rB1, 0); RDB1(Bf1[1], rB1, 1);
    STAGE_(gB1 + s0 * 32, wB2 + 8192);
    SB0; BAR; SB0;
    PRIO1; MFMA8(AHi0, Bf0, 1, 1); PRIO0;
    // ---- p5: MFMA (0,0) t1 ----
    SB0;
    RDB1(Bf1[2], rB1, 2); RDB1(Bf1[3], rB1, 3);
    STAGE_(sA1_0, wA3);
    SB0; BAR; SB0;
    PRIO1; MFMA8(ALo1, Bf1, 0, 0); PRIO0;
    // ---- p6: MFMA (0,1) t1 ----
    SB0;
    RDA(AHi1, rA1, 1);
    STAGE_(sA1_1, wA3 + 8192);
    SB0; BAR; SB0;
    PRIO1; MFMA8(ALo1, Bf1, 0, 1); PRIO0;
    // ---- p7: MFMA (1,0) t1 ----
    SB0;
    STAGE_(gB0 + s1 * 32, wB3);
    SB0; VMC(3); BAR; SB0;
    PRIO1; MFMA8(AHi1, Bf1, 1, 0); PRIO0;
    // ---- p8: MFMA (1,1) t1 ; reads roll over to next iteration ----
    SB0;
    RDA(ALo0, wA2, 0);
    RDB1(Bf0[0], wB2, 0); RDB1(Bf0[1], wB2, 1);
    STAGE_(gB1 + s1 * 32, wB3 + 8192);
    SB0; BAR; SB0;
    PRIO1; MFMA8(AHi1, Bf1, 1, 1); PRIO0;
  }

  // ---- fused epilogue. C/D layout: col = lane&15, row = (lane>>4)*4 + reg ----
  const int cr = (lane >> 4) << 2;
  const int cc = lane & 15;
#pragma unroll
  for (int i = 0; i < 8; i++) {
#pragma unroll
    for (int j = 0; j < 4; j++) {
#pragma unroll
      for (int e = 0; e < 4; e++) {
        const int m = bm + wm * 128 + i * 16 + cr + e;
        const int n = bn + wn * 64 + j * 16 + cc;
        const float v = acc[i][j][e];
        if (MODE == 0) {
          if (n < H_DIM) {
            const float g = sigmoidf_(v + bias0[n]);
            const float a = g * h_prev[(long long)m * H_DIM + n];
            xa[(long long)m * KC + IN_DIM + n] = f2bf(a);
          } else {
            const int nz = n - H_DIM;
            const float g = sigmoidf_(v + bias1[nz]);
            zbuf[(long long)m * H_DIM + nz] = g;
          }
        } else {
          const float ht = tanhf_(v + bias0[n]);
          const long long off = (long long)m * H_DIM + n;
          const float z = zbuf[off];
          const float h = h_prev[off];
          out[off] = (1.f - z) * h + z * ht;
        }
      }
    }
  }
}

// ---------- launch ----------
static inline void launch_cvt(const float* src, unsigned short* dst, int rows, int cols,
                              int src_ld, int dst_ld, hipStream_t stream) {
  long long total = (long long)rows * cols;
  int threads = 256;
  int blocks = (int)((total / 4 + threads - 1) / threads);
  cvt_kernel<<<blocks, threads, 0, stream>>>(src, dst, rows, cols, src_ld, dst_ld);
}

extern "C" void kernel_launch(void* const* d_in, const int* in_sizes, int n_in,
                              void* d_out, int out_size, void* d_ws, size_t ws_size,
                              hipStream_t stream) {
  const float* x    = (const float*)d_in[0];   // (B, IN)
  const float* h    = (const float*)d_in[1];   // (B, H)
  const float* W_ir = (const float*)d_in[2];   // (H, IN)
  const float* W_iz = (const float*)d_in[3];
  const float* W_ih = (const float*)d_in[4];
  const float* W_hr = (const float*)d_in[5];   // (H, H)
  const float* W_hz = (const float*)d_in[6];
  const float* W_hh = (const float*)d_in[7];
  const float* b_r  = (const float*)d_in[8];
  const float* b_z  = (const float*)d_in[9];
  const float* b_h  = (const float*)d_in[10];
  float* out = (float*)d_out;

  // workspace layout (bytes)
  char* ws = (char*)d_ws;
  unsigned short* xh  = (unsigned short*)(ws);                      // B x KC bf16
  unsigned short* xa  = (unsigned short*)(ws + 50331648LL);         // B x KC bf16 (only k>=IN region used)
  unsigned short* Wrz = (unsigned short*)(ws + 100663296LL);        // 2H x KC bf16
  unsigned short* Wh  = (unsigned short*)(ws + 125829120LL);        // H x KC bf16
  // z is stashed fp32 in d_out between GEMM_A and GEMM_B.

  // ---- pack inputs & weights to bf16 ----
  launch_cvt(x, xh, B_DIM, IN_DIM, IN_DIM, KC, stream);
  launch_cvt(h, xh + IN_DIM, B_DIM, H_DIM, H_DIM, KC, stream);
  launch_cvt(W_ir, Wrz, H_DIM, IN_DIM, IN_DIM, KC, stream);
  launch_cvt(W_hr, Wrz + IN_DIM, H_DIM, H_DIM, H_DIM, KC, stream);
  launch_cvt(W_iz, Wrz + (long long)H_DIM * KC, H_DIM, IN_DIM, IN_DIM, KC, stream);
  launch_cvt(W_hz, Wrz + (long long)H_DIM * KC + IN_DIM, H_DIM, H_DIM, H_DIM, KC, stream);
  launch_cvt(W_ih, Wh, H_DIM, IN_DIM, IN_DIM, KC, stream);
  launch_cvt(W_hh, Wh + IN_DIM, H_DIM, H_DIM, H_DIM, KC, stream);

  // ---- GEMM_A: [x|h] @ Wrz^T -> r,z gates; writes a into xa, z into d_out ----
  {
    const int ntiln = 4096 / 256;                 // 16
    dim3 grid((B_DIM / 256) * ntiln);             // 512 blocks (%8==0)
    gemm256<0><<<grid, 512, 0, stream>>>(xh, xh, 0, Wrz, ntiln,
                                         b_r, b_z, h, xa, out, nullptr);
  }
  // ---- GEMM_B: [x (from xh) | a (from xa)] @ Wh^T -> h_tilde; final h_t ----
  {
    const int ntiln = 2048 / 256;                 // 8
    dim3 grid((B_DIM / 256) * ntiln);             // 256 blocks (%8==0)
    gemm256<1><<<grid, 512, 0, stream>>>(xh, xa, IN_DIM / 32, Wh, ntiln,
                                         b_h, nullptr, h, nullptr, out, out);
  }
}